// Round 5
// baseline (442.756 us; speedup 1.0000x reference)
//
#include <hip/hip_runtime.h>

typedef _Float16 f16;
typedef _Float16 f16x2 __attribute__((ext_vector_type(2)));
typedef _Float16 f16x4 __attribute__((ext_vector_type(4)));
typedef _Float16 f16x8 __attribute__((ext_vector_type(8)));
typedef float f32x16 __attribute__((ext_vector_type(16)));

#define DEV __device__ __forceinline__
#define MFMA16(a, b, cc) __builtin_amdgcn_mfma_f32_32x32x16_f16(a, b, cc, 0, 0, 0)

// ---------------- problem constants ----------------
// B=131072, LATENT=32, COND=96, INPUT=128, HIDDEN=128, OUT=64, E=8, GH=128, INTER=160

// workspace (f16 element offsets) — packed weight fragments
constexpr int OFF_W0 = 0;        // 8 experts * S8  * CT4 * 64 * 8 = 131072
constexpr int OFF_W1 = 131072;   // 8 * S10 * CT4 * 64 * 8 = 163840
constexpr int OFF_W2 = 294912;   // 163840
constexpr int OFF_W3 = 458752;   // 8 * S10 * CT2 * 64 * 8 = 81920
constexpr int OFF_G0 = 540672;   // S8 * CT4 * 64 * 8 = 16384
constexpr int OFF_G1 = 557056;   // 16384
constexpr int OFF_B0 = 573440;   // CT4 * 64 * 8 = 2048
constexpr int OFF_B1 = 575488;
constexpr int OFF_B2 = 577536;
constexpr int OFF_B3 = 579584;   // CT2 * 64 * 8 = 1024
// total f16 elems = 580608  (1161216 bytes of d_ws)

// ---------------- weight repack kernel ----------------
// packed[e][s][ct][lane][i] = w[e][s*16 + (lane>>5)*8 + i][ct*32 + (lane&31)]
// so a wave ds_read_b128 at ((s*CT+ct)*64 + lane)*16 yields the exact B-fragment
// for v_mfma_f32_32x32x16_f16 (B[k][n]: n = lane&31, k = (lane>>5)*8 + i).
__global__ __launch_bounds__(256) void repack_kernel(
    const float* __restrict__ w0, const float* __restrict__ w1,
    const float* __restrict__ w2, const float* __restrict__ w3,
    const float* __restrict__ gw0, const float* __restrict__ gw1,
    const float* __restrict__ b0, const float* __restrict__ b1,
    const float* __restrict__ b2, const float* __restrict__ b3,
    f16* __restrict__ ws)
{
  int g = blockIdx.x * 256 + threadIdx.x;
  if (g < 71680) {
    const float* src; int S, CT, K, dstoff, lg;
    if (g < 16384)      { src = w0;  S = 8;  CT = 4; K = 128; dstoff = OFF_W0; lg = g; }
    else if (g < 36864) { src = w1;  S = 10; CT = 4; K = 128; dstoff = OFF_W1; lg = g - 16384; }
    else if (g < 57344) { src = w2;  S = 10; CT = 4; K = 128; dstoff = OFF_W2; lg = g - 36864; }
    else if (g < 67584) { src = w3;  S = 10; CT = 2; K = 64;  dstoff = OFF_W3; lg = g - 57344; }
    else if (g < 69632) { src = gw0; S = 8;  CT = 4; K = 128; dstoff = OFF_G0; lg = g - 67584; }
    else                { src = gw1; S = 8;  CT = 4; K = 128; dstoff = OFF_G1; lg = g - 69632; }
    int l = lg & 63;
    int t = lg >> 6;
    int ct = t % CT; t /= CT;
    int s = t % S;
    int e = t / S;
    int J = S * 16;
    int n  = ct * 32 + (l & 31);
    int jb = s * 16 + (l >> 5) * 8;
    f16* dst = ws + dstoff + (size_t)lg * 8;
#pragma unroll
    for (int i = 0; i < 8; ++i)
      dst[i] = (f16)src[((size_t)(e * J + jb + i)) * K + n];
  } else if (g < 72576) {
    // packed bias: pb[ct][lane][i] = (lane<32) ? bias[i][ct*32+lane] : 0
    int bg = g - 71680;
    const float* src; int K, dstoff, lb;
    if (bg < 256)      { src = b0; K = 128; dstoff = OFF_B0; lb = bg; }
    else if (bg < 512) { src = b1; K = 128; dstoff = OFF_B1; lb = bg - 256; }
    else if (bg < 768) { src = b2; K = 128; dstoff = OFF_B2; lb = bg - 512; }
    else               { src = b3; K = 64;  dstoff = OFF_B3; lb = bg - 768; }
    int l = lb & 63, ct = lb >> 6;
    int n = ct * 32 + (l & 31);
    f16* dst = ws + dstoff + (size_t)lb * 8;
#pragma unroll
    for (int i = 0; i < 8; ++i)
      dst[i] = (l < 32) ? (f16)src[i * K + n] : (f16)0.0f;
  }
}

// ---------------- fused kernel helpers ----------------
// swizzled activation LDS: fp16 [256 rows][128 cols], pitch 256B.
// XOR byte-bits 4..7 with (row&15): 32 lanes reading 32 distinct rows at one
// column slice land on 16 distinct 16B slots -> 2-way aliasing only (free).
DEV unsigned char* actsp(unsigned char* acts, int row, int colb) {
  return acts + (((row << 8) + colb) ^ ((row & 15) << 4));
}

DEV f16x8 cvt8(float4 a, float4 b) {
  f16x8 r;
  r[0] = (f16)a.x; r[1] = (f16)a.y; r[2] = (f16)a.z; r[3] = (f16)a.w;
  r[4] = (f16)b.x; r[5] = (f16)b.y; r[6] = (f16)b.z; r[7] = (f16)b.w;
  return r;
}

template <int NR, int NC>
DEV void zacc(f32x16 (&a)[NR][NC]) {
#pragma unroll
  for (int rt = 0; rt < NR; ++rt)
#pragma unroll
    for (int t = 0; t < NC; ++t)
#pragma unroll
      for (int i = 0; i < 16; ++i) a[rt][t][i] = 0.f;
}

// per-row mean/rsqrt(var+eps) from fp16 fragments; lane l and l^32 hold
// complementary j-halves of the same row -> one shfl_xor(32) completes the row.
template <int NF>
DEV void rowstats(const f16x8 (&F)[NF], float invJ, float& mu, float& rs) {
  float s1 = 0.f, s2 = 0.f;
#if __has_builtin(__builtin_amdgcn_fdot2)
  const f16x2 one2 = {(f16)1.0f, (f16)1.0f};
#pragma unroll
  for (int i = 0; i < NF; ++i) {
    union { f16x8 v; f16x2 p[4]; } u;
    u.v = F[i];
#pragma unroll
    for (int q = 0; q < 4; ++q) {
      s1 = __builtin_amdgcn_fdot2(u.p[q], one2, s1, false);
      s2 = __builtin_amdgcn_fdot2(u.p[q], u.p[q], s2, false);
    }
  }
#else
#pragma unroll
  for (int i = 0; i < NF; ++i)
#pragma unroll
    for (int q = 0; q < 8; ++q) {
      float v = (float)F[i][q];
      s1 += v;
      s2 += v * v;
    }
#endif
  s1 += __shfl_xor(s1, 32, 64);
  s2 += __shfl_xor(s2, 32, 64);
  mu = s1 * invJ;
  float var = s2 * invJ - mu * mu;
  rs = rsqrtf(var + 1e-5f);
}

// expert loop: 8 experts, double-buffered LDS weights, LN+coeff fused into A.
// unroll 2 -> ping-pong buffer selects become compile-time.
template <int NS, int NCTW, int CTTOT, int N16>
DEV void expert_loop(const f16x8 (&F0)[NS], const f16x8 (&F1)[NS],
                     float mu0, float rs0, float mu1, float rs1,
                     unsigned char* wb0, unsigned char* wb1,
                     const f16x8 cf0, const f16x8 cf1,
                     const f16* wsrc, const f16* nextsrc, int next_n16,
                     int ct0, int lane, int tid,
                     f32x16 (&acc)[2][NCTW]) {
#pragma unroll 2
  for (int e = 0; e < 8; ++e) {
    unsigned char* rb  = (e & 1) ? wb1 : wb0;
    unsigned char* wbn = (e & 1) ? wb0 : wb1;
    const float4* src = (const float4*)((e < 7) ? (wsrc + (size_t)(e + 1) * N16 * 8) : nextsrc);
    int n16 = (e < 7) ? N16 : next_n16;
    float4 stg[5];
#pragma unroll
    for (int k = 0; k < 5; ++k) {
      int idx = tid + k * 512;
      if (idx < n16) stg[k] = src[idx];
    }
    float p0f = rs0 * (float)cf0[e], p1f = rs1 * (float)cf1[e];
    f16 p0 = (f16)p0f, q0 = (f16)(-mu0 * p0f);
    f16 p1 = (f16)p1f, q1 = (f16)(-mu1 * p1f);
#pragma unroll
    for (int s = 0; s < NS; ++s) {
      f16x8 a0 = F0[s] * p0 + q0;
      f16x8 a1 = F1[s] * p1 + q1;
#pragma unroll
      for (int t = 0; t < NCTW; ++t) {
        f16x8 b = *(const f16x8*)(rb + (size_t)(((s * CTTOT) + (ct0 + t)) * 64 + lane) * 16);
        acc[0][t] = MFMA16(a0, b, acc[0][t]);
        acc[1][t] = MFMA16(a1, b, acc[1][t]);
      }
    }
#pragma unroll
    for (int k = 0; k < 5; ++k) {
      int idx = tid + k * 512;
      if (idx < n16) *(float4*)(wbn + (size_t)idx * 16) = stg[k];
    }
    __syncthreads();
  }
}

// mixed_bias = coeff @ b as one extra MFMA: A = coeff (k<8; k>=8 side of B is 0)
template <int NCTW>
DEV void bias_mfma(f32x16 (&acc)[2][NCTW], const f16x8 ca0, const f16x8 ca1,
                   const f16* pb, int ct0, int lane) {
#pragma unroll
  for (int t = 0; t < NCTW; ++t) {
    f16x8 bb = *(const f16x8*)(pb + (size_t)((ct0 + t) * 64 + lane) * 8);
    acc[0][t] = MFMA16(ca0, bb, acc[0][t]);
    acc[1][t] = MFMA16(ca1, bb, acc[1][t]);
  }
}

template <int NCTW>
DEV void store_acts(const f32x16 (&acc)[2][NCTW], unsigned char* acts,
                    int wrow, int ct0, int lr, int h) {
#pragma unroll
  for (int t = 0; t < NCTW; ++t) {
    int col = (ct0 + t) * 32 + lr;
#pragma unroll
    for (int rt = 0; rt < 2; ++rt) {
#pragma unroll
      for (int r = 0; r < 16; ++r) {
        float v = acc[rt][t][r];
        v = v > 0.f ? v : __expf(v) - 1.f;   // ELU
        int rowl = (r & 3) + 8 * (r >> 2) + 4 * h;
        *(f16*)actsp(acts, wrow * 64 + rt * 32 + rowl, col * 2) = (f16)v;
      }
    }
  }
}

// ---------------- fused decoder kernel ----------------
__global__ __launch_bounds__(512, 2) void moe_fused(
    const float* __restrict__ z, const float* __restrict__ c,
    const float* __restrict__ gb0, const float* __restrict__ gb1,
    const float* __restrict__ gw2, const float* __restrict__ gb2,
    const f16* __restrict__ ws, float* __restrict__ out)
{
  __shared__ __align__(16) unsigned char smem[151552];
  unsigned char* wb0  = smem;                 // 40960: weight ping
  unsigned char* wb1  = smem + 40960;         // 40960: weight pong
  unsigned char* acts = smem + 81920;         // 65536: fp16 [256][128] swizzled
  f16* coeffH = (f16*)(smem + 147456);        // [256][8] fp16 (4096 B)

  const int tid  = threadIdx.x;
  const int lane = tid & 63;
  const int wave = tid >> 6;
  const int wrow = wave >> 1, wc = wave & 1;
  const int h = lane >> 5, lr = lane & 31;
  const int brow = blockIdx.x << 8;
  const int lrow0 = wrow * 64 + lr, lrow1 = lrow0 + 32;
  const int ct0 = wc * 2;

  // ---- stage x = [z|c] as fp16 into acts ----
  {
    int row = tid >> 1, half = tid & 1;
    const float* zr = z + (size_t)(brow + row) * 32;
    const float* cr = c + (size_t)(brow + row) * 96;
#pragma unroll
    for (int jj = 0; jj < 16; ++jj) {
      int j0 = half * 64 + jj * 4;
      float4 v = (j0 < 32) ? *(const float4*)(zr + j0)
                           : *(const float4*)(cr + (j0 - 32));
      f16x4 hv = {(f16)v.x, (f16)v.y, (f16)v.z, (f16)v.w};
      *(f16x4*)actsp(acts, row, j0 * 2) = hv;
    }
  }
  float4 stgA[4];
  { // issue gw0
    const float4* g4 = (const float4*)(ws + OFF_G0);
#pragma unroll
    for (int k = 0; k < 4; ++k) stgA[k] = g4[tid + k * 512];
  }
  __syncthreads();  // x ready

  // ---- commit gw0; read x fragments; LN(x) stats (for layer 0) ----
#pragma unroll
  for (int k = 0; k < 4; ++k) *(float4*)(wb0 + (size_t)(tid + k * 512) * 16) = stgA[k];
  f16x8 FX0[8], FX1[8];
#pragma unroll
  for (int s = 0; s < 8; ++s) {
    FX0[s] = *(const f16x8*)actsp(acts, lrow0, s * 32 + h * 16);
    FX1[s] = *(const f16x8*)actsp(acts, lrow1, s * 32 + h * 16);
  }
  float mu0, rs0, mu1, rs1;
  rowstats<8>(FX0, 1.f / 128.f, mu0, rs0);
  rowstats<8>(FX1, 1.f / 128.f, mu1, rs1);
  { // issue gw1
    const float4* g4 = (const float4*)(ws + OFF_G1);
#pragma unroll
    for (int k = 0; k < 4; ++k) stgA[k] = g4[tid + k * 512];
  }
  __syncthreads();  // gw0 ready; all x-fragment reads done

  // ---- gate GEMM1: h = elu(x @ gw0 + gb0) ----
  f32x16 acc[2][2];
  zacc(acc);
#pragma unroll
  for (int s = 0; s < 8; ++s) {
    f16x8 b0 = *(const f16x8*)(wb0 + (size_t)((s * 4 + ct0) * 64 + lane) * 16);
    f16x8 b1 = *(const f16x8*)(wb0 + (size_t)((s * 4 + ct0 + 1) * 64 + lane) * 16);
    acc[0][0] = MFMA16(FX0[s], b0, acc[0][0]);
    acc[0][1] = MFMA16(FX0[s], b1, acc[0][1]);
    acc[1][0] = MFMA16(FX1[s], b0, acc[1][0]);
    acc[1][1] = MFMA16(FX1[s], b1, acc[1][1]);
  }
#pragma unroll
  for (int t = 0; t < 2; ++t) {
    int col = (ct0 + t) * 32 + lr;
    float bias = gb0[col];
#pragma unroll
    for (int rt = 0; rt < 2; ++rt)
#pragma unroll
      for (int r = 0; r < 16; ++r) {
        float v = acc[rt][t][r] + bias;
        v = v > 0.f ? v : __expf(v) - 1.f;
        int rowl = (r & 3) + 8 * (r >> 2) + 4 * h;
        *(f16*)actsp(acts, wrow * 64 + rt * 32 + rowl, col * 2) = (f16)v;
      }
  }
#pragma unroll
  for (int k = 0; k < 4; ++k) *(float4*)(wb1 + (size_t)(tid + k * 512) * 16) = stgA[k];
  __syncthreads();  // h ready; gw1 ready

  // ---- gate GEMM2: h2 = elu(h @ gw1 + gb1) ----
  zacc(acc);
#pragma unroll
  for (int s = 0; s < 8; ++s) {
    f16x8 a0 = *(const f16x8*)actsp(acts, lrow0, s * 32 + h * 16);
    f16x8 a1 = *(const f16x8*)actsp(acts, lrow1, s * 32 + h * 16);
    f16x8 b0 = *(const f16x8*)(wb1 + (size_t)((s * 4 + ct0) * 64 + lane) * 16);
    f16x8 b1 = *(const f16x8*)(wb1 + (size_t)((s * 4 + ct0 + 1) * 64 + lane) * 16);
    acc[0][0] = MFMA16(a0, b0, acc[0][0]);
    acc[0][1] = MFMA16(a0, b1, acc[0][1]);
    acc[1][0] = MFMA16(a1, b0, acc[1][0]);
    acc[1][1] = MFMA16(a1, b1, acc[1][1]);
  }
  { // issue w0 expert0
    const float4* g4 = (const float4*)(ws + OFF_W0);
#pragma unroll
    for (int k = 0; k < 4; ++k) stgA[k] = g4[tid + k * 512];
  }
  __syncthreads();  // all h reads done
#pragma unroll
  for (int t = 0; t < 2; ++t) {
    int col = (ct0 + t) * 32 + lr;
    float bias = gb1[col];
#pragma unroll
    for (int rt = 0; rt < 2; ++rt)
#pragma unroll
      for (int r = 0; r < 16; ++r) {
        float v = acc[rt][t][r] + bias;
        v = v > 0.f ? v : __expf(v) - 1.f;
        int rowl = (r & 3) + 8 * (r >> 2) + 4 * h;
        *(f16*)actsp(acts, wrow * 64 + rt * 32 + rowl, col * 2) = (f16)v;
      }
  }
#pragma unroll
  for (int k = 0; k < 4; ++k) *(float4*)(wb0 + (size_t)(tid + k * 512) * 16) = stgA[k];
  __syncthreads();  // h2 ready; w0e0 ready

  // ---- gate GEMM3 (K=8, VALU) + softmax -> coeff ----
  {
    int row = tid >> 1, part = tid & 1;
    float lgt[8];
#pragma unroll
    for (int e = 0; e < 8; ++e) lgt[e] = 0.f;
#pragma unroll
    for (int q = 0; q < 8; ++q) {
      f16x8 hv = *(const f16x8*)actsp(acts, row, part * 128 + q * 16);
#pragma unroll
      for (int i = 0; i < 8; ++i) {
        float hf = (float)hv[i];
        int j = part * 64 + q * 8 + i;
        const float4* gp = (const float4*)(gw2 + j * 8);
        float4 ga = gp[0], gb = gp[1];
        lgt[0] += hf * ga.x; lgt[1] += hf * ga.y; lgt[2] += hf * ga.z; lgt[3] += hf * ga.w;
        lgt[4] += hf * gb.x; lgt[5] += hf * gb.y; lgt[6] += hf * gb.z; lgt[7] += hf * gb.w;
      }
    }
#pragma unroll
    for (int e = 0; e < 8; ++e) {
      lgt[e] += __shfl_xor(lgt[e], 1, 64);
      lgt[e] += gb2[e];
    }
    float m = lgt[0];
#pragma unroll
    for (int e = 1; e < 8; ++e) m = fmaxf(m, lgt[e]);
    float ssum = 0.f, pe[8];
#pragma unroll
    for (int e = 0; e < 8; ++e) { pe[e] = __expf(lgt[e] - m); ssum += pe[e]; }
    float inv = 1.f / ssum;
    if (part == 0) {
      f16x8 ch;
#pragma unroll
      for (int e = 0; e < 8; ++e) ch[e] = (f16)(pe[e] * inv);
      *(f16x8*)(coeffH + row * 8) = ch;
    }
  }
  __syncthreads();  // coeff ready

  // per-row coeff fragments, reused for all 4 layers (A of bias-MFMA + mix scale)
  const f16x8 cf0 = *(const f16x8*)(coeffH + lrow0 * 8);
  const f16x8 cf1 = *(const f16x8*)(coeffH + lrow1 * 8);

  // ---- layer 0: inp = LN(x), J=128, K=128 (x frags + stats still in regs) ----
  zacc(acc);
  expert_loop<8, 2, 4, 2048>(FX0, FX1, mu0, rs0, mu1, rs1, wb0, wb1, cf0, cf1,
                             ws + OFF_W0, ws + OFF_W1, 2560,
                             ct0, lane, tid, acc);
  bias_mfma<2>(acc, cf0, cf1, ws + OFF_B0, ct0, lane);
  store_acts<2>(acc, acts, wrow, ct0, lr, h);
  __syncthreads();  // layer0 out complete; w1e0 staged

  // ---- layers 1..3: inp = LN([z | prev]), J=160 ----
  f16x8 F0[10], F1[10];
  auto load_layer_frags = [&]() {
#pragma unroll
    for (int s = 0; s < 2; ++s) {  // z part from global (L2-resident)
      const float* zp0 = z + (size_t)(brow + lrow0) * 32 + s * 16 + h * 8;
      const float* zp1 = z + (size_t)(brow + lrow1) * 32 + s * 16 + h * 8;
      float4 a0 = *(const float4*)zp0, a1 = *(const float4*)(zp0 + 4);
      float4 b0_ = *(const float4*)zp1, b1_ = *(const float4*)(zp1 + 4);
      F0[s] = cvt8(a0, a1);
      F1[s] = cvt8(b0_, b1_);
    }
#pragma unroll
    for (int s = 0; s < 8; ++s) {
      F0[2 + s] = *(const f16x8*)actsp(acts, lrow0, s * 32 + h * 16);
      F1[2 + s] = *(const f16x8*)actsp(acts, lrow1, s * 32 + h * 16);
    }
    rowstats<10>(F0, 1.f / 160.f, mu0, rs0);
    rowstats<10>(F1, 1.f / 160.f, mu1, rs1);
  };

  // layer 1
  load_layer_frags();
  zacc(acc);
  expert_loop<10, 2, 4, 2560>(F0, F1, mu0, rs0, mu1, rs1, wb0, wb1, cf0, cf1,
                              ws + OFF_W1, ws + OFF_W2, 2560,
                              ct0, lane, tid, acc);
  bias_mfma<2>(acc, cf0, cf1, ws + OFF_B1, ct0, lane);
  store_acts<2>(acc, acts, wrow, ct0, lr, h);
  __syncthreads();

  // layer 2
  load_layer_frags();
  zacc(acc);
  expert_loop<10, 2, 4, 2560>(F0, F1, mu0, rs0, mu1, rs1, wb0, wb1, cf0, cf1,
                              ws + OFF_W2, ws + OFF_W3, 1280,
                              ct0, lane, tid, acc);
  bias_mfma<2>(acc, cf0, cf1, ws + OFF_B2, ct0, lane);
  store_acts<2>(acc, acts, wrow, ct0, lr, h);
  __syncthreads();

  // layer 3 (K=64, no activation, fp32 out)
  load_layer_frags();
  f32x16 acc3[2][1];
  zacc(acc3);
  expert_loop<10, 1, 2, 1280>(F0, F1, mu0, rs0, mu1, rs1, wb0, wb1, cf0, cf1,
                              ws + OFF_W3, ws /*dummy*/, 0,
                              wc, lane, tid, acc3);
  bias_mfma<1>(acc3, cf0, cf1, ws + OFF_B3, wc, lane);
  {
    int col = wc * 32 + lr;
#pragma unroll
    for (int rt = 0; rt < 2; ++rt)
#pragma unroll
      for (int r = 0; r < 16; ++r) {
        int rowl = (r & 3) + 8 * (r >> 2) + 4 * h;
        int grow = brow + wrow * 64 + rt * 32 + rowl;
        out[(size_t)grow * 64 + col] = acc3[rt][0][r];
      }
  }
}

// ---------------- launch ----------------
extern "C" void kernel_launch(void* const* d_in, const int* in_sizes, int n_in,
                              void* d_out, int out_size, void* d_ws, size_t ws_size,
                              hipStream_t stream) {
  (void)in_sizes; (void)n_in; (void)out_size; (void)ws_size;
  const float* z   = (const float*)d_in[0];
  const float* c   = (const float*)d_in[1];
  const float* w0  = (const float*)d_in[2];
  const float* b0  = (const float*)d_in[3];
  const float* w1  = (const float*)d_in[4];
  const float* b1  = (const float*)d_in[5];
  const float* w2  = (const float*)d_in[6];
  const float* b2  = (const float*)d_in[7];
  const float* w3  = (const float*)d_in[8];
  const float* b3  = (const float*)d_in[9];
  const float* gw0 = (const float*)d_in[10];
  const float* gb0 = (const float*)d_in[11];
  const float* gw1 = (const float*)d_in[12];
  const float* gb1 = (const float*)d_in[13];
  const float* gw2 = (const float*)d_in[14];
  const float* gb2 = (const float*)d_in[15];
  f16* ws = (f16*)d_ws;
  float* out = (float*)d_out;

  repack_kernel<<<dim3(284), dim3(256), 0, stream>>>(
      w0, w1, w2, w3, gw0, gw1, b0, b1, b2, b3, ws);
  moe_fused<<<dim3(512), dim3(512), 0, stream>>>(
      z, c, gb0, gb1, gw2, gb2, ws, out);
}